// Round 1
// baseline (1359.783 us; speedup 1.0000x reference)
//
#include <hip/hip_runtime.h>

#define NN 100000
#define NE 1600000
#define INF 128
#define HID 150
#define NOUT 128

// ---------------- CSR build ----------------

__global__ void count_deg(const int* __restrict__ dst, int* __restrict__ deg) {
    int i = blockIdx.x * blockDim.x + threadIdx.x;
    if (i < NE) atomicAdd(&deg[dst[i]], 1);
}

__global__ void scan_local(const int* __restrict__ deg, int* __restrict__ excl,
                           int* __restrict__ blk_sums) {
    __shared__ int s[256];
    int i = blockIdx.x * 256 + threadIdx.x;
    int d = (i < NN) ? deg[i] : 0;
    s[threadIdx.x] = d;
    __syncthreads();
    for (int off = 1; off < 256; off <<= 1) {
        int t = (threadIdx.x >= off) ? s[threadIdx.x - off] : 0;
        __syncthreads();
        s[threadIdx.x] += t;
        __syncthreads();
    }
    int incl = s[threadIdx.x];
    if (i < NN) excl[i] = incl - d;
    if (threadIdx.x == 255) blk_sums[blockIdx.x] = incl;
}

__global__ void scan_blocks(int* __restrict__ blk_sums, int nb) {
    __shared__ int s[512];
    int t = threadIdx.x;
    int v = (t < nb) ? blk_sums[t] : 0;
    s[t] = v;
    __syncthreads();
    for (int off = 1; off < 512; off <<= 1) {
        int u = (t >= off) ? s[t - off] : 0;
        __syncthreads();
        s[t] += u;
        __syncthreads();
    }
    if (t < nb) blk_sums[t] = s[t] - v;  // exclusive
}

__global__ void scan_finalize(const int* __restrict__ deg, int* __restrict__ csr_ptr,
                              const int* __restrict__ blk_sums, int* __restrict__ fill,
                              float* __restrict__ deg_inv) {
    int i = blockIdx.x * 256 + threadIdx.x;
    if (i >= NN) return;
    int p = csr_ptr[i] + blk_sums[blockIdx.x];
    csr_ptr[i] = p;
    fill[i] = p;
    int d = deg[i];
    deg_inv[i] = d > 0 ? 1.0f / (float)d : 0.0f;
}

__global__ void scatter_edges(const int* __restrict__ src, const int* __restrict__ dst,
                              int* __restrict__ fill, int* __restrict__ csr_src) {
    int i = blockIdx.x * blockDim.x + threadIdx.x;
    if (i < NE) {
        int p = atomicAdd(&fill[dst[i]], 1);
        csr_src[p] = src[i];
    }
}

// ---------------- aggregation (one wave per dst node, 128 feats = 64 lanes x float2) ----------------

__global__ __launch_bounds__(256) void agg_mean_128(
    const float* __restrict__ feat, const int* __restrict__ csr_ptr,
    const int* __restrict__ deg, const float* __restrict__ deg_inv,
    const int* __restrict__ csr_src, float* __restrict__ outbuf) {
    int wid = threadIdx.x >> 6;
    int lane = threadIdx.x & 63;
    int v = blockIdx.x * 4 + wid;
    if (v >= NN) return;
    int start = csr_ptr[v];
    int d = deg[v];
    const float2* f2 = (const float2*)feat;
    float2 acc = make_float2(0.f, 0.f);
    for (int e = start; e < start + d; ++e) {
        int s = csr_src[e];
        float2 t = f2[(size_t)s * 64 + lane];
        acc.x += t.x;
        acc.y += t.y;
    }
    float di = deg_inv[v];
    float2* o2 = (float2*)outbuf;
    o2[(size_t)v * 64 + lane] = make_float2(acc.x * di, acc.y * di);
}

__global__ __launch_bounds__(256) void agg_mean_add_out(
    const float* __restrict__ z, const int* __restrict__ csr_ptr,
    const int* __restrict__ deg, const float* __restrict__ deg_inv,
    const int* __restrict__ csr_src, float* __restrict__ out) {
    int wid = threadIdx.x >> 6;
    int lane = threadIdx.x & 63;
    int v = blockIdx.x * 4 + wid;
    if (v >= NN) return;
    int start = csr_ptr[v];
    int d = deg[v];
    const float2* z2 = (const float2*)z;
    float2 acc = make_float2(0.f, 0.f);
    for (int e = start; e < start + d; ++e) {
        int s = csr_src[e];
        float2 t = z2[(size_t)s * 64 + lane];
        acc.x += t.x;
        acc.y += t.y;
    }
    float di = deg_inv[v];
    float2* o2 = (float2*)out;
    float2 cur = o2[(size_t)v * 64 + lane];
    cur.x += acc.x * di;
    cur.y += acc.y * di;
    o2[(size_t)v * 64 + lane] = cur;
}

// ---------------- GEMMs (fp32 vector ALU, 64x32 tile, BK=32, 4x2/thread) ----------------

#define BM 64
#define BN 32
#define BK 32

// h1[100000x150] = relu([x | agg](100000x256) @ [Ws1; Wn1](256x150) + b1)
__global__ __launch_bounds__(256) void gemm1(
    const float* __restrict__ x, const float* __restrict__ agg,
    const float* __restrict__ Ws, const float* __restrict__ Wn,
    const float* __restrict__ b1, float* __restrict__ h1) {
    __shared__ float As[BK][BM + 1];
    __shared__ float Bs[BK][BN + 1];
    int m0 = blockIdx.x * BM;
    int n0 = blockIdx.y * BN;
    int tid = threadIdx.x;
    int tx = tid & 15, ty = tid >> 4;
    float acc[4][2] = {};
    for (int k0 = 0; k0 < 256; k0 += BK) {
        #pragma unroll
        for (int l = 0; l < 8; l++) {
            int idx = tid + l * 256;
            int k = idx & 31, m = idx >> 5;
            int gm = m0 + m, gk = k0 + k;
            float v = 0.f;
            if (gm < NN)
                v = (gk < 128) ? x[(size_t)gm * 128 + gk] : agg[(size_t)gm * 128 + (gk - 128)];
            As[k][m] = v;
        }
        #pragma unroll
        for (int l = 0; l < 4; l++) {
            int idx = tid + l * 256;
            int n = idx & 31, k = idx >> 5;
            int gk = k0 + k, gn = n0 + n;
            float v = 0.f;
            if (gn < HID)
                v = (gk < 128) ? Ws[(size_t)gk * HID + gn] : Wn[(size_t)(gk - 128) * HID + gn];
            Bs[k][n] = v;
        }
        __syncthreads();
        #pragma unroll
        for (int kk = 0; kk < BK; kk++) {
            float a[4], b[2];
            #pragma unroll
            for (int i = 0; i < 4; i++) a[i] = As[kk][ty * 4 + i];
            b[0] = Bs[kk][tx * 2];
            b[1] = Bs[kk][tx * 2 + 1];
            #pragma unroll
            for (int i = 0; i < 4; i++) {
                acc[i][0] += a[i] * b[0];
                acc[i][1] += a[i] * b[1];
            }
        }
        __syncthreads();
    }
    #pragma unroll
    for (int i = 0; i < 4; i++) {
        int gm = m0 + ty * 4 + i;
        if (gm >= NN) continue;
        #pragma unroll
        for (int j = 0; j < 2; j++) {
            int gn = n0 + tx * 2 + j;
            if (gn < HID) {
                float v = acc[i][j] + b1[gn];
                h1[(size_t)gm * HID + gn] = v > 0.f ? v : 0.f;
            }
        }
    }
}

// out_self[100000x128] = h1 @ Ws2 + b2 (cols 0..127);  z[100000x128] = h1 @ Wn2 (cols 128..255)
__global__ __launch_bounds__(256) void gemm2(
    const float* __restrict__ h1, const float* __restrict__ Ws,
    const float* __restrict__ Wn, const float* __restrict__ b2,
    float* __restrict__ out, float* __restrict__ z) {
    __shared__ float As[BK][BM + 1];
    __shared__ float Bs[BK][BN + 1];
    int m0 = blockIdx.x * BM;
    int n0 = blockIdx.y * BN;
    int tid = threadIdx.x;
    int tx = tid & 15, ty = tid >> 4;
    float acc[4][2] = {};
    for (int k0 = 0; k0 < 160; k0 += BK) {
        #pragma unroll
        for (int l = 0; l < 8; l++) {
            int idx = tid + l * 256;
            int k = idx & 31, m = idx >> 5;
            int gm = m0 + m, gk = k0 + k;
            float v = 0.f;
            if (gm < NN && gk < HID) v = h1[(size_t)gm * HID + gk];
            As[k][m] = v;
        }
        #pragma unroll
        for (int l = 0; l < 4; l++) {
            int idx = tid + l * 256;
            int n = idx & 31, k = idx >> 5;
            int gk = k0 + k, gn = n0 + n;
            float v = 0.f;
            if (gk < HID)
                v = (gn < 128) ? Ws[(size_t)gk * 128 + gn] : Wn[(size_t)gk * 128 + (gn - 128)];
            Bs[k][n] = v;
        }
        __syncthreads();
        #pragma unroll
        for (int kk = 0; kk < BK; kk++) {
            float a[4], b[2];
            #pragma unroll
            for (int i = 0; i < 4; i++) a[i] = As[kk][ty * 4 + i];
            b[0] = Bs[kk][tx * 2];
            b[1] = Bs[kk][tx * 2 + 1];
            #pragma unroll
            for (int i = 0; i < 4; i++) {
                acc[i][0] += a[i] * b[0];
                acc[i][1] += a[i] * b[1];
            }
        }
        __syncthreads();
    }
    #pragma unroll
    for (int i = 0; i < 4; i++) {
        int gm = m0 + ty * 4 + i;
        if (gm >= NN) continue;
        #pragma unroll
        for (int j = 0; j < 2; j++) {
            int gn = n0 + tx * 2 + j;
            if (gn < 128) {
                out[(size_t)gm * 128 + gn] = acc[i][j] + b2[gn];
            } else {
                z[(size_t)gm * 128 + (gn - 128)] = acc[i][j];
            }
        }
    }
}

// ---------------- launch ----------------

extern "C" void kernel_launch(void* const* d_in, const int* in_sizes, int n_in,
                              void* d_out, int out_size, void* d_ws, size_t ws_size,
                              hipStream_t stream) {
    const float* x   = (const float*)d_in[0];
    const int* src   = (const int*)d_in[1];
    const int* dst   = (const int*)d_in[2];
    const float* Ws1 = (const float*)d_in[3];
    const float* Wn1 = (const float*)d_in[4];
    const float* b1  = (const float*)d_in[5];
    const float* Ws2 = (const float*)d_in[6];
    const float* Wn2 = (const float*)d_in[7];
    const float* b2  = (const float*)d_in[8];
    float* out = (float*)d_out;

    // workspace carve (256B aligned)
    char* p = (char*)d_ws;
    auto carve = [&](size_t bytes) {
        void* r = (void*)p;
        p += (bytes + 255) & ~(size_t)255;
        return r;
    };
    int*   deg      = (int*)carve(NN * 4);
    int*   csr_ptr  = (int*)carve(NN * 4);
    int*   fill     = (int*)carve(NN * 4);
    float* deg_inv  = (float*)carve(NN * 4);
    int*   blk_sums = (int*)carve(512 * 4);
    int*   csr_src  = (int*)carve((size_t)NE * 4);
    float* agg      = (float*)carve((size_t)NN * 128 * 4);  // reused as z in layer 2
    float* h1       = (float*)carve((size_t)NN * HID * 4);
    float* z        = agg;

    const int NB = (NN + 255) / 256;  // 391

    hipMemsetAsync(deg, 0, NN * 4, stream);
    count_deg<<<(NE + 255) / 256, 256, 0, stream>>>(dst, deg);
    scan_local<<<NB, 256, 0, stream>>>(deg, csr_ptr, blk_sums);
    scan_blocks<<<1, 512, 0, stream>>>(blk_sums, NB);
    scan_finalize<<<NB, 256, 0, stream>>>(deg, csr_ptr, blk_sums, fill, deg_inv);
    scatter_edges<<<(NE + 255) / 256, 256, 0, stream>>>(src, dst, fill, csr_src);

    // layer 1: aggregate x, fused GEMM K=256 (self||neigh), +bias, relu
    agg_mean_128<<<NN / 4, 256, 0, stream>>>(x, csr_ptr, deg, deg_inv, csr_src, agg);
    {
        dim3 grid((NN + BM - 1) / BM, (HID + BN - 1) / BN);
        gemm1<<<grid, 256, 0, stream>>>(x, agg, Ws1, Wn1, b1, h1);
    }
    // layer 2: fused GEMM N=256 -> out(self)+z(neigh pre-agg), then aggregate z into out
    {
        dim3 grid((NN + BM - 1) / BM, (NOUT * 2) / BN);
        gemm2<<<grid, 256, 0, stream>>>(h1, Ws2, Wn2, b2, out, z);
    }
    agg_mean_add_out<<<NN / 4, 256, 0, stream>>>(z, csr_ptr, deg, deg_inv, csr_src, out);

    (void)in_sizes; (void)n_in; (void)out_size; (void)ws_size;
}

// Round 2
// 583.111 us; speedup vs baseline: 2.3319x; 2.3319x over previous
//
#include <hip/hip_runtime.h>

#define NN 100000
#define NE 1600000
#define INF 128
#define HID 150
#define NOUT 128

typedef __attribute__((ext_vector_type(8))) short bf16x8;
typedef __attribute__((ext_vector_type(8))) unsigned short u16x8;
typedef __attribute__((ext_vector_type(4))) float f32x4;

__device__ inline unsigned short f2bf(float f) {
    unsigned int u = __float_as_uint(f);
    u += 0x7fffu + ((u >> 16) & 1u);
    return (unsigned short)(u >> 16);
}
__device__ inline float bf2f(unsigned int hi16) {
    return __uint_as_float(hi16 << 16);
}

// ---------------- CSR build ----------------

__global__ void count_deg(const int* __restrict__ dst, int* __restrict__ deg) {
    int i = blockIdx.x * blockDim.x + threadIdx.x;
    if (i < NE) atomicAdd(&deg[dst[i]], 1);
}

__global__ void scan_local(const int* __restrict__ deg, int* __restrict__ excl,
                           int* __restrict__ blk_sums) {
    __shared__ int s[256];
    int i = blockIdx.x * 256 + threadIdx.x;
    int d = (i < NN) ? deg[i] : 0;
    s[threadIdx.x] = d;
    __syncthreads();
    for (int off = 1; off < 256; off <<= 1) {
        int t = (threadIdx.x >= off) ? s[threadIdx.x - off] : 0;
        __syncthreads();
        s[threadIdx.x] += t;
        __syncthreads();
    }
    int incl = s[threadIdx.x];
    if (i < NN) excl[i] = incl - d;
    if (threadIdx.x == 255) blk_sums[blockIdx.x] = incl;
}

__global__ void scan_blocks(int* __restrict__ blk_sums, int nb) {
    __shared__ int s[512];
    int t = threadIdx.x;
    int v = (t < nb) ? blk_sums[t] : 0;
    s[t] = v;
    __syncthreads();
    for (int off = 1; off < 512; off <<= 1) {
        int u = (t >= off) ? s[t - off] : 0;
        __syncthreads();
        s[t] += u;
        __syncthreads();
    }
    if (t < nb) blk_sums[t] = s[t] - v;  // exclusive
}

__global__ void scan_finalize(const int* __restrict__ deg, int* __restrict__ csr_ptr,
                              const int* __restrict__ blk_sums, int* __restrict__ fill,
                              float* __restrict__ deg_inv) {
    int i = blockIdx.x * 256 + threadIdx.x;
    if (i >= NN) return;
    int p = csr_ptr[i] + blk_sums[blockIdx.x];
    csr_ptr[i] = p;
    fill[i] = p;
    int d = deg[i];
    deg_inv[i] = d > 0 ? 1.0f / (float)d : 0.0f;
}

__global__ void scatter_edges(const int* __restrict__ src, const int* __restrict__ dst,
                              int* __restrict__ fill, int* __restrict__ csr_src) {
    int i = blockIdx.x * blockDim.x + threadIdx.x;
    if (i < NE) {
        int p = atomicAdd(&fill[dst[i]], 1);
        csr_src[p] = src[i];
    }
}

// ---------------- casts / packing ----------------

// fp32 -> bf16, 8 elems per thread
__global__ void cast_bf16(const float* __restrict__ in, unsigned short* __restrict__ outb,
                          int n8) {
    int i = blockIdx.x * 256 + threadIdx.x;
    if (i >= n8) return;
    const float4* p = (const float4*)in;
    float4 v0 = p[(size_t)i * 2];
    float4 v1 = p[(size_t)i * 2 + 1];
    u16x8 o = {f2bf(v0.x), f2bf(v0.y), f2bf(v0.z), f2bf(v0.w),
               f2bf(v1.x), f2bf(v1.y), f2bf(v1.z), f2bf(v1.w)};
    ((u16x8*)outb)[i] = o;
}

// Pack W1t[n][k] (160x256, bf16): B for layer 1, transposed, zero-padded n>=150.
// Pack W2t[n][k] (256x160, bf16): B for layer 2, transposed, zero-padded k>=150.
// Pack b1p[160] fp32 (zero tail).
__global__ void pack_weights(const float* __restrict__ Ws1, const float* __restrict__ Wn1,
                             const float* __restrict__ b1,
                             const float* __restrict__ Ws2, const float* __restrict__ Wn2,
                             unsigned short* __restrict__ W1t, unsigned short* __restrict__ W2t,
                             float* __restrict__ b1p) {
    int id = blockIdx.x * 256 + threadIdx.x;
    if (id < 160 * 256) {
        int n = id >> 8, k = id & 255;
        float v = 0.f;
        if (n < HID) v = (k < 128) ? Ws1[k * HID + n] : Wn1[(k - 128) * HID + n];
        W1t[id] = f2bf(v);
    } else if (id < 160 * 256 + 256 * 160) {
        int id2 = id - 160 * 256;
        int n = id2 / 160, k = id2 - n * 160;
        float v = 0.f;
        if (k < HID) v = (n < 128) ? Ws2[k * 128 + n] : Wn2[k * 128 + (n - 128)];
        W2t[id2] = f2bf(v);
    } else if (id < 160 * 256 + 256 * 160 + 160) {
        int n = id - (160 * 256 + 256 * 160);
        b1p[n] = (n < HID) ? b1[n] : 0.f;
    }
}

// ---------------- aggregation (bf16 gather, fp32 accumulate) ----------------

__global__ __launch_bounds__(256) void agg_mean_bf16(
    const unsigned short* __restrict__ featb, const int* __restrict__ csr_ptr,
    const int* __restrict__ deg, const float* __restrict__ deg_inv,
    const int* __restrict__ csr_src, unsigned short* __restrict__ outb) {
    int wid = threadIdx.x >> 6;
    int lane = threadIdx.x & 63;
    int v = blockIdx.x * 4 + wid;
    int start = csr_ptr[v];
    int d = deg[v];
    const unsigned int* f = (const unsigned int*)featb;  // 2 bf16 per uint
    float ax = 0.f, ay = 0.f;
    int e = start, end = start + d;
    for (; e + 1 < end; e += 2) {
        int s0 = csr_src[e], s1 = csr_src[e + 1];
        unsigned int t0 = f[(size_t)s0 * 64 + lane];
        unsigned int t1 = f[(size_t)s1 * 64 + lane];
        ax += bf2f(t0 & 0xffffu) + bf2f(t1 & 0xffffu);
        ay += bf2f(t0 >> 16) + bf2f(t1 >> 16);
    }
    if (e < end) {
        int s0 = csr_src[e];
        unsigned int t0 = f[(size_t)s0 * 64 + lane];
        ax += bf2f(t0 & 0xffffu);
        ay += bf2f(t0 >> 16);
    }
    float di = deg_inv[v];
    unsigned int o = (unsigned int)f2bf(ax * di) | ((unsigned int)f2bf(ay * di) << 16);
    ((unsigned int*)outb)[(size_t)v * 64 + lane] = o;
}

__global__ __launch_bounds__(256) void agg_add_out(
    const unsigned short* __restrict__ zb, const int* __restrict__ csr_ptr,
    const int* __restrict__ deg, const float* __restrict__ deg_inv,
    const int* __restrict__ csr_src, float* __restrict__ out) {
    int wid = threadIdx.x >> 6;
    int lane = threadIdx.x & 63;
    int v = blockIdx.x * 4 + wid;
    int start = csr_ptr[v];
    int d = deg[v];
    const unsigned int* f = (const unsigned int*)zb;
    float ax = 0.f, ay = 0.f;
    int e = start, end = start + d;
    for (; e + 1 < end; e += 2) {
        int s0 = csr_src[e], s1 = csr_src[e + 1];
        unsigned int t0 = f[(size_t)s0 * 64 + lane];
        unsigned int t1 = f[(size_t)s1 * 64 + lane];
        ax += bf2f(t0 & 0xffffu) + bf2f(t1 & 0xffffu);
        ay += bf2f(t0 >> 16) + bf2f(t1 >> 16);
    }
    if (e < end) {
        int s0 = csr_src[e];
        unsigned int t0 = f[(size_t)s0 * 64 + lane];
        ax += bf2f(t0 & 0xffffu);
        ay += bf2f(t0 >> 16);
    }
    float di = deg_inv[v];
    float2* o2 = (float2*)out;
    float2 cur = o2[(size_t)v * 64 + lane];
    cur.x += ax * di;
    cur.y += ay * di;
    o2[(size_t)v * 64 + lane] = cur;
}

// ---------------- MFMA GEMMs ----------------
// 16x16x32 bf16 MFMA. Verified layouts:
//   A-frag: lane holds A[m=lane&15][k=quad*8+j]  (8 contig bf16 -> ds_read_b128)
//   B-frag: lane holds B[k=quad*8+j][n=lane&15]  -> store B transposed Bt[n][k] in LDS
//   C/D:    col=lane&15, row=quad*4+reg
// LDS rows padded to 40 bf16 (80 B): frag reads land 2 lanes/bank (free).

// layer 1: h1b[100000x160 bf16] = relu([xb|aggb](Mx256) @ W1t^T + b1p), N tile = 160
__global__ __launch_bounds__(256) void gemm1_mfma(
    const unsigned short* __restrict__ xb, const unsigned short* __restrict__ aggb,
    const unsigned short* __restrict__ W1t, const float* __restrict__ b1p,
    unsigned short* __restrict__ h1b) {
    __shared__ __align__(16) unsigned short A_lds[128][40];
    __shared__ __align__(16) unsigned short B_lds[160][40];
    int tid = threadIdx.x;
    int m0 = blockIdx.x * 128;
    int w = tid >> 6, lane = tid & 63;
    int lrow = lane & 15, quad = lane >> 4;
    int wr = (w & 1) * 64;   // wave row base
    int wc = (w >> 1) * 80;  // wave col base (5 tiles of 16)
    f32x4 acc[4][5];
    #pragma unroll
    for (int r = 0; r < 4; r++)
        #pragma unroll
        for (int c = 0; c < 5; c++) acc[r][c] = (f32x4){0.f, 0.f, 0.f, 0.f};

    for (int k0 = 0; k0 < 256; k0 += 32) {
        __syncthreads();
        // stage A: 128 rows x 4 chunks of 8 bf16
        #pragma unroll
        for (int i = 0; i < 2; i++) {
            int idx = tid + i * 256;
            int row = idx >> 2, ch = idx & 3;
            int gm = m0 + row, gk = k0 + ch * 8;
            u16x8 val = {0, 0, 0, 0, 0, 0, 0, 0};
            if (gm < NN) {
                const unsigned short* sp = (gk < 128)
                    ? (xb + (size_t)gm * 128 + gk)
                    : (aggb + (size_t)gm * 128 + (gk - 128));
                val = *(const u16x8*)sp;
            }
            *(u16x8*)&A_lds[row][ch * 8] = val;
        }
        // stage B: 160 rows x 4 chunks
        #pragma unroll
        for (int i = 0; i < 3; i++) {
            int idx = tid + i * 256;
            if (idx < 640) {
                int n = idx >> 2, ch = idx & 3;
                u16x8 val = *(const u16x8*)(W1t + (size_t)n * 256 + k0 + ch * 8);
                *(u16x8*)&B_lds[n][ch * 8] = val;
            }
        }
        __syncthreads();
        bf16x8 a[4], b[5];
        #pragma unroll
        for (int r = 0; r < 4; r++)
            a[r] = *(const bf16x8*)&A_lds[wr + r * 16 + lrow][quad * 8];
        #pragma unroll
        for (int c = 0; c < 5; c++)
            b[c] = *(const bf16x8*)&B_lds[wc + c * 16 + lrow][quad * 8];
        #pragma unroll
        for (int r = 0; r < 4; r++)
            #pragma unroll
            for (int c = 0; c < 5; c++)
                acc[r][c] = __builtin_amdgcn_mfma_f32_16x16x32_bf16(a[r], b[c], acc[r][c], 0, 0, 0);
    }
    // epilogue: bias + relu + bf16 store (stride 160; cols>=150 are 0 by construction)
    #pragma unroll
    for (int r = 0; r < 4; r++) {
        #pragma unroll
        for (int rr = 0; rr < 4; rr++) {
            int gm = m0 + wr + r * 16 + quad * 4 + rr;
            if (gm < NN) {
                #pragma unroll
                for (int c = 0; c < 5; c++) {
                    int gn = wc + c * 16 + lrow;
                    float val = acc[r][c][rr] + b1p[gn];
                    val = val > 0.f ? val : 0.f;
                    h1b[(size_t)gm * 160 + gn] = f2bf(val);
                }
            }
        }
    }
}

// layer 2: blockIdx.y==0 -> out(fp32)=h1b@Ws2+b2 ; blockIdx.y==1 -> zb(bf16)=h1b@Wn2
__global__ __launch_bounds__(256) void gemm2_mfma(
    const unsigned short* __restrict__ h1b, const unsigned short* __restrict__ W2t,
    const float* __restrict__ b2, float* __restrict__ out,
    unsigned short* __restrict__ zb) {
    __shared__ __align__(16) unsigned short A_lds[128][40];
    __shared__ __align__(16) unsigned short B_lds[128][40];
    int tid = threadIdx.x;
    int m0 = blockIdx.x * 128;
    int n0 = blockIdx.y * 128;
    int w = tid >> 6, lane = tid & 63;
    int lrow = lane & 15, quad = lane >> 4;
    int wr = (w & 1) * 64;
    int wc = (w >> 1) * 64;
    f32x4 acc[4][4];
    #pragma unroll
    for (int r = 0; r < 4; r++)
        #pragma unroll
        for (int c = 0; c < 4; c++) acc[r][c] = (f32x4){0.f, 0.f, 0.f, 0.f};

    for (int k0 = 0; k0 < 160; k0 += 32) {
        __syncthreads();
        #pragma unroll
        for (int i = 0; i < 2; i++) {
            int idx = tid + i * 256;
            int row = idx >> 2, ch = idx & 3;
            int gm = m0 + row;
            u16x8 val = {0, 0, 0, 0, 0, 0, 0, 0};
            if (gm < NN) val = *(const u16x8*)(h1b + (size_t)gm * 160 + k0 + ch * 8);
            *(u16x8*)&A_lds[row][ch * 8] = val;
        }
        #pragma unroll
        for (int i = 0; i < 2; i++) {
            int idx = tid + i * 256;
            int n = idx >> 2, ch = idx & 3;
            u16x8 val = *(const u16x8*)(W2t + (size_t)(n0 + n) * 160 + k0 + ch * 8);
            *(u16x8*)&B_lds[n][ch * 8] = val;
        }
        __syncthreads();
        bf16x8 a[4], b[4];
        #pragma unroll
        for (int r = 0; r < 4; r++)
            a[r] = *(const bf16x8*)&A_lds[wr + r * 16 + lrow][quad * 8];
        #pragma unroll
        for (int c = 0; c < 4; c++)
            b[c] = *(const bf16x8*)&B_lds[wc + c * 16 + lrow][quad * 8];
        #pragma unroll
        for (int r = 0; r < 4; r++)
            #pragma unroll
            for (int c = 0; c < 4; c++)
                acc[r][c] = __builtin_amdgcn_mfma_f32_16x16x32_bf16(a[r], b[c], acc[r][c], 0, 0, 0);
    }
    #pragma unroll
    for (int r = 0; r < 4; r++) {
        #pragma unroll
        for (int rr = 0; rr < 4; rr++) {
            int gm = m0 + wr + r * 16 + quad * 4 + rr;
            if (gm < NN) {
                #pragma unroll
                for (int c = 0; c < 4; c++) {
                    int gn = wc + c * 16 + lrow;  // local col 0..127
                    float val = acc[r][c][rr];
                    if (n0 == 0) {
                        out[(size_t)gm * 128 + gn] = val + b2[gn];
                    } else {
                        zb[(size_t)gm * 128 + gn] = f2bf(val);
                    }
                }
            }
        }
    }
}

// ---------------- launch ----------------

extern "C" void kernel_launch(void* const* d_in, const int* in_sizes, int n_in,
                              void* d_out, int out_size, void* d_ws, size_t ws_size,
                              hipStream_t stream) {
    const float* x   = (const float*)d_in[0];
    const int* src   = (const int*)d_in[1];
    const int* dst   = (const int*)d_in[2];
    const float* Ws1 = (const float*)d_in[3];
    const float* Wn1 = (const float*)d_in[4];
    const float* b1  = (const float*)d_in[5];
    const float* Ws2 = (const float*)d_in[6];
    const float* Wn2 = (const float*)d_in[7];
    const float* b2  = (const float*)d_in[8];
    float* out = (float*)d_out;

    char* p = (char*)d_ws;
    auto carve = [&](size_t bytes) {
        void* r = (void*)p;
        p += (bytes + 255) & ~(size_t)255;
        return r;
    };
    int*   deg      = (int*)carve(NN * 4);
    int*   csr_ptr  = (int*)carve(NN * 4);
    int*   fill     = (int*)carve(NN * 4);
    float* deg_inv  = (float*)carve(NN * 4);
    int*   blk_sums = (int*)carve(512 * 4);
    int*   csr_src  = (int*)carve((size_t)NE * 4);
    unsigned short* xb   = (unsigned short*)carve((size_t)NN * 128 * 2);
    unsigned short* aggb = (unsigned short*)carve((size_t)NN * 128 * 2);
    unsigned short* h1b  = (unsigned short*)carve((size_t)NN * 160 * 2);
    unsigned short* zb   = (unsigned short*)carve((size_t)NN * 128 * 2);
    unsigned short* W1t  = (unsigned short*)carve(160 * 256 * 2);
    unsigned short* W2t  = (unsigned short*)carve(256 * 160 * 2);
    float* b1p           = (float*)carve(160 * 4);

    const int NB = (NN + 255) / 256;  // 391

    hipMemsetAsync(deg, 0, NN * 4, stream);
    count_deg<<<(NE + 255) / 256, 256, 0, stream>>>(dst, deg);
    scan_local<<<NB, 256, 0, stream>>>(deg, csr_ptr, blk_sums);
    scan_blocks<<<1, 512, 0, stream>>>(blk_sums, NB);
    scan_finalize<<<NB, 256, 0, stream>>>(deg, csr_ptr, blk_sums, fill, deg_inv);
    scatter_edges<<<(NE + 255) / 256, 256, 0, stream>>>(src, dst, fill, csr_src);

    // casts + weight packing (independent of CSR)
    cast_bf16<<<(NN * 128 / 8 + 255) / 256, 256, 0, stream>>>(x, xb, NN * 128 / 8);
    pack_weights<<<(160 * 256 + 256 * 160 + 160 + 255) / 256, 256, 0, stream>>>(
        Ws1, Wn1, b1, Ws2, Wn2, W1t, W2t, b1p);

    // layer 1
    agg_mean_bf16<<<NN / 4, 256, 0, stream>>>(xb, csr_ptr, deg, deg_inv, csr_src, aggb);
    gemm1_mfma<<<dim3((NN + 127) / 128, 1), 256, 0, stream>>>(xb, aggb, W1t, b1p, h1b);

    // layer 2
    gemm2_mfma<<<dim3((NN + 127) / 128, 2), 256, 0, stream>>>(h1b, W2t, b2, out, zb);
    agg_add_out<<<NN / 4, 256, 0, stream>>>(zb, csr_ptr, deg, deg_inv, csr_src, out);

    (void)in_sizes; (void)n_in; (void)out_size; (void)ws_size;
}

// Round 3
// 457.459 us; speedup vs baseline: 2.9725x; 1.2747x over previous
//
#include <hip/hip_runtime.h>

#define NN 100000
#define NE 1600000
#define INF 128
#define HID 150
#define NOUT 128

// radix-by-bucket CSR build params
#define NBK 196        // buckets = ceil(NN/512); bucket(d) = d>>9
#define WGS 400        // sort workgroups
#define EPW 4000       // edges per sort workgroup (WGS*EPW == NE exactly)
#define CNTL (NBK * WGS)
#define CAP2 10240     // LDS span cap in buildcsr (mean 8192, +22 sigma)

typedef __attribute__((ext_vector_type(8))) short bf16x8;
typedef __attribute__((ext_vector_type(8))) unsigned short u16x8;
typedef __attribute__((ext_vector_type(4))) float f32x4;

__device__ inline unsigned short f2bf(float f) {
    unsigned int u = __float_as_uint(f);
    u += 0x7fffu + ((u >> 16) & 1u);
    return (unsigned short)(u >> 16);
}
__device__ inline float bf2f(unsigned int hi16) {
    return __uint_as_float(hi16 << 16);
}

// ---------------- radix sort by dst bucket ----------------

// Per-WG: histogram 196 buckets, LDS scan, LDS scatter (word = (dst&511)<<17 | src),
// coalesced chunk write. cntm[b*WGS + w] = count.
__global__ __launch_bounds__(256) void sort1(const int* __restrict__ src,
                                             const int* __restrict__ dst,
                                             unsigned int* __restrict__ chunkw,
                                             int* __restrict__ cntm) {
    __shared__ int hist[NBK];
    __shared__ int off[NBK];
    __shared__ int s[256];
    __shared__ unsigned int buf[EPW];
    int w = blockIdx.x, tid = threadIdx.x;
    int e0 = w * EPW;
    for (int i = tid; i < NBK; i += 256) hist[i] = 0;
    __syncthreads();
    for (int i = tid; i < EPW; i += 256) atomicAdd(&hist[dst[e0 + i] >> 9], 1);
    __syncthreads();
    int v = (tid < NBK) ? hist[tid] : 0;
    s[tid] = v;
    __syncthreads();
    for (int o = 1; o < 256; o <<= 1) {
        int t = (tid >= o) ? s[tid - o] : 0;
        __syncthreads();
        s[tid] += t;
        __syncthreads();
    }
    if (tid < NBK) {
        off[tid] = s[tid] - v;          // exclusive
        cntm[tid * WGS + w] = v;
    }
    __syncthreads();
    for (int i = tid; i < EPW; i += 256) {
        int d = dst[e0 + i];
        int b = d >> 9;
        int p = atomicAdd(&off[b], 1);
        buf[p] = (unsigned int)src[e0 + i] | ((unsigned int)(d & 511) << 17);
    }
    __syncthreads();
    for (int i = tid; i < EPW; i += 256) chunkw[e0 + i] = buf[i];
}

// hierarchical exclusive scan of cntm (length CNTL) -> offm
__global__ void scanA(const int* __restrict__ in, int* __restrict__ excl,
                      int* __restrict__ blk_sums, int L) {
    __shared__ int s[256];
    int i = blockIdx.x * 256 + threadIdx.x;
    int d = (i < L) ? in[i] : 0;
    s[threadIdx.x] = d;
    __syncthreads();
    for (int o = 1; o < 256; o <<= 1) {
        int t = (threadIdx.x >= o) ? s[threadIdx.x - o] : 0;
        __syncthreads();
        s[threadIdx.x] += t;
        __syncthreads();
    }
    int incl = s[threadIdx.x];
    if (i < L) excl[i] = incl - d;
    if (threadIdx.x == 255) blk_sums[blockIdx.x] = incl;
}

__global__ void scanB(int* __restrict__ blk_sums, int nb) {
    __shared__ int s[512];
    int t = threadIdx.x;
    int v = (t < nb) ? blk_sums[t] : 0;
    s[t] = v;
    __syncthreads();
    for (int o = 1; o < 512; o <<= 1) {
        int u = (t >= o) ? s[t - o] : 0;
        __syncthreads();
        s[t] += u;
        __syncthreads();
    }
    if (t < nb) blk_sums[t] = s[t] - v;  // exclusive
}

__global__ void scanC(int* __restrict__ excl, const int* __restrict__ blk_sums, int L) {
    int i = blockIdx.x * 256 + threadIdx.x;
    if (i < L) excl[i] += blk_sums[blockIdx.x];
}

// Redistribute each WG's sorted chunk into bucket-major order.
__global__ __launch_bounds__(256) void sort3(const unsigned int* __restrict__ chunkw,
                                             const int* __restrict__ cntm,
                                             const int* __restrict__ offm,
                                             unsigned int* __restrict__ bmaj) {
    __shared__ int excl[NBK + 1];
    __shared__ int dbase[NBK];
    __shared__ int s[256];
    int w = blockIdx.x, tid = threadIdx.x;
    int v = (tid < NBK) ? cntm[tid * WGS + w] : 0;
    if (tid < NBK) dbase[tid] = offm[tid * WGS + w];
    s[tid] = v;
    __syncthreads();
    for (int o = 1; o < 256; o <<= 1) {
        int t = (tid >= o) ? s[tid - o] : 0;
        __syncthreads();
        s[tid] += t;
        __syncthreads();
    }
    if (tid < NBK) excl[tid] = s[tid] - v;
    if (tid == 0) excl[NBK] = EPW;
    __syncthreads();
    int e0 = w * EPW;
    for (int i = tid; i < EPW; i += 256) {
        int lo = 0, hi = NBK;
        while (hi - lo > 1) {
            int mid = (lo + hi) >> 1;
            if (excl[mid] <= i) lo = mid; else hi = mid;
        }
        bmaj[dbase[lo] + (i - excl[lo])] = chunkw[e0 + i];
    }
}

// One WG per bucket: degrees, csr_ptr, deg_inv, scatter srcs to LDS span, coalesced out.
__global__ __launch_bounds__(256) void buildcsr(const unsigned int* __restrict__ bmaj,
                                                const int* __restrict__ offm,
                                                int* __restrict__ csr_ptr,
                                                float* __restrict__ deg_inv,
                                                int* __restrict__ csr_src) {
    __shared__ int cnt[512];
    __shared__ int excl[512];
    __shared__ int off[512];
    __shared__ int s[256];
    __shared__ int span[CAP2];
    int b = blockIdx.x, tid = threadIdx.x;
    int base = offm[b * WGS];
    int nxt = (b == NBK - 1) ? NE : offm[(b + 1) * WGS];
    int n = nxt - base;
    if (n > CAP2) n = CAP2;  // memory-safety clamp (never hit for this input)
    for (int i = tid; i < 512; i += 256) cnt[i] = 0;
    __syncthreads();
    for (int i = tid; i < n; i += 256) atomicAdd(&cnt[bmaj[base + i] >> 17], 1);
    __syncthreads();
    int a0 = cnt[2 * tid], a1 = cnt[2 * tid + 1];
    int ps = a0 + a1;
    s[tid] = ps;
    __syncthreads();
    for (int o = 1; o < 256; o <<= 1) {
        int t = (tid >= o) ? s[tid - o] : 0;
        __syncthreads();
        s[tid] += t;
        __syncthreads();
    }
    int ex = s[tid] - ps;
    excl[2 * tid] = ex;
    excl[2 * tid + 1] = ex + a0;
    off[2 * tid] = ex;
    off[2 * tid + 1] = ex + a0;
    __syncthreads();
    for (int l = tid; l < 512; l += 256) {
        int g = b * 512 + l;
        if (g < NN) {
            csr_ptr[g] = base + excl[l];
            int d = cnt[l];
            deg_inv[g] = d > 0 ? 1.0f / (float)d : 0.0f;
        }
    }
    if (b == NBK - 1 && tid == 0) csr_ptr[NN] = NE;
    for (int i = tid; i < n; i += 256) {
        unsigned int wd = bmaj[base + i];
        int l = wd >> 17;
        int p = atomicAdd(&off[l], 1);
        span[p] = (int)(wd & 0x1FFFFu);
    }
    __syncthreads();
    for (int i = tid; i < n; i += 256) csr_src[base + i] = span[i];
}

// ---------------- casts / packing ----------------

__global__ void cast_bf16(const float* __restrict__ in, unsigned short* __restrict__ outb,
                          int n8) {
    int i = blockIdx.x * 256 + threadIdx.x;
    if (i >= n8) return;
    const float4* p = (const float4*)in;
    float4 v0 = p[(size_t)i * 2];
    float4 v1 = p[(size_t)i * 2 + 1];
    u16x8 o = {f2bf(v0.x), f2bf(v0.y), f2bf(v0.z), f2bf(v0.w),
               f2bf(v1.x), f2bf(v1.y), f2bf(v1.z), f2bf(v1.w)};
    ((u16x8*)outb)[i] = o;
}

__global__ void pack_weights(const float* __restrict__ Ws1, const float* __restrict__ Wn1,
                             const float* __restrict__ b1,
                             const float* __restrict__ Ws2, const float* __restrict__ Wn2,
                             unsigned short* __restrict__ W1t, unsigned short* __restrict__ W2t,
                             float* __restrict__ b1p) {
    int id = blockIdx.x * 256 + threadIdx.x;
    if (id < 160 * 256) {
        int n = id >> 8, k = id & 255;
        float v = 0.f;
        if (n < HID) v = (k < 128) ? Ws1[k * HID + n] : Wn1[(k - 128) * HID + n];
        W1t[id] = f2bf(v);
    } else if (id < 160 * 256 + 256 * 160) {
        int id2 = id - 160 * 256;
        int n = id2 / 160, k = id2 - n * 160;
        float v = 0.f;
        if (k < HID) v = (n < 128) ? Ws2[k * 128 + n] : Wn2[k * 128 + (n - 128)];
        W2t[id2] = f2bf(v);
    } else if (id < 160 * 256 + 256 * 160 + 160) {
        int n = id - (160 * 256 + 256 * 160);
        b1p[n] = (n < HID) ? b1[n] : 0.f;
    }
}

// ---------------- aggregation (bf16 gather, fp32 accumulate) ----------------

__global__ __launch_bounds__(256) void agg_mean_bf16(
    const unsigned short* __restrict__ featb, const int* __restrict__ csr_ptr,
    const float* __restrict__ deg_inv, const int* __restrict__ csr_src,
    unsigned short* __restrict__ outb) {
    int wid = threadIdx.x >> 6;
    int lane = threadIdx.x & 63;
    int v = blockIdx.x * 4 + wid;
    int start = csr_ptr[v];
    int end = csr_ptr[v + 1];
    const unsigned int* f = (const unsigned int*)featb;
    float ax = 0.f, ay = 0.f;
    int e = start;
    for (; e + 1 < end; e += 2) {
        int s0 = csr_src[e], s1 = csr_src[e + 1];
        unsigned int t0 = f[(size_t)s0 * 64 + lane];
        unsigned int t1 = f[(size_t)s1 * 64 + lane];
        ax += bf2f(t0 & 0xffffu) + bf2f(t1 & 0xffffu);
        ay += bf2f(t0 >> 16) + bf2f(t1 >> 16);
    }
    if (e < end) {
        int s0 = csr_src[e];
        unsigned int t0 = f[(size_t)s0 * 64 + lane];
        ax += bf2f(t0 & 0xffffu);
        ay += bf2f(t0 >> 16);
    }
    float di = deg_inv[v];
    unsigned int o = (unsigned int)f2bf(ax * di) | ((unsigned int)f2bf(ay * di) << 16);
    ((unsigned int*)outb)[(size_t)v * 64 + lane] = o;
}

__global__ __launch_bounds__(256) void agg_add_out(
    const unsigned short* __restrict__ zb, const int* __restrict__ csr_ptr,
    const float* __restrict__ deg_inv, const int* __restrict__ csr_src,
    float* __restrict__ out) {
    int wid = threadIdx.x >> 6;
    int lane = threadIdx.x & 63;
    int v = blockIdx.x * 4 + wid;
    int start = csr_ptr[v];
    int end = csr_ptr[v + 1];
    const unsigned int* f = (const unsigned int*)zb;
    float ax = 0.f, ay = 0.f;
    int e = start;
    for (; e + 1 < end; e += 2) {
        int s0 = csr_src[e], s1 = csr_src[e + 1];
        unsigned int t0 = f[(size_t)s0 * 64 + lane];
        unsigned int t1 = f[(size_t)s1 * 64 + lane];
        ax += bf2f(t0 & 0xffffu) + bf2f(t1 & 0xffffu);
        ay += bf2f(t0 >> 16) + bf2f(t1 >> 16);
    }
    if (e < end) {
        int s0 = csr_src[e];
        unsigned int t0 = f[(size_t)s0 * 64 + lane];
        ax += bf2f(t0 & 0xffffu);
        ay += bf2f(t0 >> 16);
    }
    float di = deg_inv[v];
    float2* o2 = (float2*)out;
    float2 cur = o2[(size_t)v * 64 + lane];
    cur.x += ax * di;
    cur.y += ay * di;
    o2[(size_t)v * 64 + lane] = cur;
}

// ---------------- MFMA GEMMs ----------------

__global__ __launch_bounds__(256) void gemm1_mfma(
    const unsigned short* __restrict__ xb, const unsigned short* __restrict__ aggb,
    const unsigned short* __restrict__ W1t, const float* __restrict__ b1p,
    unsigned short* __restrict__ h1b) {
    __shared__ __align__(16) unsigned short A_lds[128][40];
    __shared__ __align__(16) unsigned short B_lds[160][40];
    int tid = threadIdx.x;
    int m0 = blockIdx.x * 128;
    int w = tid >> 6, lane = tid & 63;
    int lrow = lane & 15, quad = lane >> 4;
    int wr = (w & 1) * 64;
    int wc = (w >> 1) * 80;
    f32x4 acc[4][5];
    #pragma unroll
    for (int r = 0; r < 4; r++)
        #pragma unroll
        for (int c = 0; c < 5; c++) acc[r][c] = (f32x4){0.f, 0.f, 0.f, 0.f};

    for (int k0 = 0; k0 < 256; k0 += 32) {
        __syncthreads();
        #pragma unroll
        for (int i = 0; i < 2; i++) {
            int idx = tid + i * 256;
            int row = idx >> 2, ch = idx & 3;
            int gm = m0 + row, gk = k0 + ch * 8;
            u16x8 val = {0, 0, 0, 0, 0, 0, 0, 0};
            if (gm < NN) {
                const unsigned short* sp = (gk < 128)
                    ? (xb + (size_t)gm * 128 + gk)
                    : (aggb + (size_t)gm * 128 + (gk - 128));
                val = *(const u16x8*)sp;
            }
            *(u16x8*)&A_lds[row][ch * 8] = val;
        }
        #pragma unroll
        for (int i = 0; i < 3; i++) {
            int idx = tid + i * 256;
            if (idx < 640) {
                int n = idx >> 2, ch = idx & 3;
                u16x8 val = *(const u16x8*)(W1t + (size_t)n * 256 + k0 + ch * 8);
                *(u16x8*)&B_lds[n][ch * 8] = val;
            }
        }
        __syncthreads();
        bf16x8 a[4], b[5];
        #pragma unroll
        for (int r = 0; r < 4; r++)
            a[r] = *(const bf16x8*)&A_lds[wr + r * 16 + lrow][quad * 8];
        #pragma unroll
        for (int c = 0; c < 5; c++)
            b[c] = *(const bf16x8*)&B_lds[wc + c * 16 + lrow][quad * 8];
        #pragma unroll
        for (int r = 0; r < 4; r++)
            #pragma unroll
            for (int c = 0; c < 5; c++)
                acc[r][c] = __builtin_amdgcn_mfma_f32_16x16x32_bf16(a[r], b[c], acc[r][c], 0, 0, 0);
    }
    #pragma unroll
    for (int r = 0; r < 4; r++) {
        #pragma unroll
        for (int rr = 0; rr < 4; rr++) {
            int gm = m0 + wr + r * 16 + quad * 4 + rr;
            if (gm < NN) {
                #pragma unroll
                for (int c = 0; c < 5; c++) {
                    int gn = wc + c * 16 + lrow;
                    float val = acc[r][c][rr] + b1p[gn];
                    val = val > 0.f ? val : 0.f;
                    h1b[(size_t)gm * 160 + gn] = f2bf(val);
                }
            }
        }
    }
}

__global__ __launch_bounds__(256) void gemm2_mfma(
    const unsigned short* __restrict__ h1b, const unsigned short* __restrict__ W2t,
    const float* __restrict__ b2, float* __restrict__ out,
    unsigned short* __restrict__ zb) {
    __shared__ __align__(16) unsigned short A_lds[128][40];
    __shared__ __align__(16) unsigned short B_lds[128][40];
    int tid = threadIdx.x;
    int m0 = blockIdx.x * 128;
    int n0 = blockIdx.y * 128;
    int w = tid >> 6, lane = tid & 63;
    int lrow = lane & 15, quad = lane >> 4;
    int wr = (w & 1) * 64;
    int wc = (w >> 1) * 64;
    f32x4 acc[4][4];
    #pragma unroll
    for (int r = 0; r < 4; r++)
        #pragma unroll
        for (int c = 0; c < 4; c++) acc[r][c] = (f32x4){0.f, 0.f, 0.f, 0.f};

    for (int k0 = 0; k0 < 160; k0 += 32) {
        __syncthreads();
        #pragma unroll
        for (int i = 0; i < 2; i++) {
            int idx = tid + i * 256;
            int row = idx >> 2, ch = idx & 3;
            int gm = m0 + row;
            u16x8 val = {0, 0, 0, 0, 0, 0, 0, 0};
            if (gm < NN) val = *(const u16x8*)(h1b + (size_t)gm * 160 + k0 + ch * 8);
            *(u16x8*)&A_lds[row][ch * 8] = val;
        }
        #pragma unroll
        for (int i = 0; i < 2; i++) {
            int idx = tid + i * 256;
            int n = idx >> 2, ch = idx & 3;
            u16x8 val = *(const u16x8*)(W2t + (size_t)(n0 + n) * 160 + k0 + ch * 8);
            *(u16x8*)&B_lds[n][ch * 8] = val;
        }
        __syncthreads();
        bf16x8 a[4], b[4];
        #pragma unroll
        for (int r = 0; r < 4; r++)
            a[r] = *(const bf16x8*)&A_lds[wr + r * 16 + lrow][quad * 8];
        #pragma unroll
        for (int c = 0; c < 4; c++)
            b[c] = *(const bf16x8*)&B_lds[wc + c * 16 + lrow][quad * 8];
        #pragma unroll
        for (int r = 0; r < 4; r++)
            #pragma unroll
            for (int c = 0; c < 4; c++)
                acc[r][c] = __builtin_amdgcn_mfma_f32_16x16x32_bf16(a[r], b[c], acc[r][c], 0, 0, 0);
    }
    #pragma unroll
    for (int r = 0; r < 4; r++) {
        #pragma unroll
        for (int rr = 0; rr < 4; rr++) {
            int gm = m0 + wr + r * 16 + quad * 4 + rr;
            if (gm < NN) {
                #pragma unroll
                for (int c = 0; c < 4; c++) {
                    int gn = wc + c * 16 + lrow;
                    float val = acc[r][c][rr];
                    if (n0 == 0) {
                        out[(size_t)gm * 128 + gn] = val + b2[gn];
                    } else {
                        zb[(size_t)gm * 128 + gn] = f2bf(val);
                    }
                }
            }
        }
    }
}

// ---------------- launch ----------------

extern "C" void kernel_launch(void* const* d_in, const int* in_sizes, int n_in,
                              void* d_out, int out_size, void* d_ws, size_t ws_size,
                              hipStream_t stream) {
    const float* x   = (const float*)d_in[0];
    const int* src   = (const int*)d_in[1];
    const int* dst   = (const int*)d_in[2];
    const float* Ws1 = (const float*)d_in[3];
    const float* Wn1 = (const float*)d_in[4];
    const float* b1  = (const float*)d_in[5];
    const float* Ws2 = (const float*)d_in[6];
    const float* Wn2 = (const float*)d_in[7];
    const float* b2  = (const float*)d_in[8];
    float* out = (float*)d_out;

    char* p = (char*)d_ws;
    auto carve = [&](size_t bytes) {
        void* r = (void*)p;
        p += (bytes + 255) & ~(size_t)255;
        return r;
    };
    int*   csr_ptr  = (int*)carve((size_t)(NN + 1) * 4);
    float* deg_inv  = (float*)carve((size_t)NN * 4);
    int*   csr_src  = (int*)carve((size_t)NE * 4);
    int*   cntm     = (int*)carve((size_t)CNTL * 4);
    int*   offm     = (int*)carve((size_t)CNTL * 4);
    int*   blk2     = (int*)carve(512 * 4);
    unsigned short* xb   = (unsigned short*)carve((size_t)NN * 128 * 2);
    unsigned short* aggb = (unsigned short*)carve((size_t)NN * 128 * 2);
    unsigned short* zb   = (unsigned short*)carve((size_t)NN * 128 * 2);
    unsigned short* W1t  = (unsigned short*)carve(160 * 256 * 2);
    unsigned short* W2t  = (unsigned short*)carve(256 * 160 * 2);
    float* b1p           = (float*)carve(160 * 4);
    unsigned short* h1b  = (unsigned short*)carve((size_t)NN * 160 * 2);
    // sort buffers alias h1b's 32 MB region (dead until gemm1 runs)
    unsigned int* chunkw = (unsigned int*)h1b;                       // 6.4 MB
    unsigned int* bmaj   = (unsigned int*)((char*)h1b + (size_t)NE * 4);  // 6.4 MB

    // CSR build: radix sort by bucket, no global atomics
    sort1<<<WGS, 256, 0, stream>>>(src, dst, chunkw, cntm);
    const int SB = (CNTL + 255) / 256;  // 307
    scanA<<<SB, 256, 0, stream>>>(cntm, offm, blk2, CNTL);
    scanB<<<1, 512, 0, stream>>>(blk2, SB);
    scanC<<<SB, 256, 0, stream>>>(offm, blk2, CNTL);
    sort3<<<WGS, 256, 0, stream>>>(chunkw, cntm, offm, bmaj);
    buildcsr<<<NBK, 256, 0, stream>>>(bmaj, offm, csr_ptr, deg_inv, csr_src);

    // casts + weight packing
    cast_bf16<<<(NN * 128 / 8 + 255) / 256, 256, 0, stream>>>(x, xb, NN * 128 / 8);
    pack_weights<<<(160 * 256 + 256 * 160 + 160 + 255) / 256, 256, 0, stream>>>(
        Ws1, Wn1, b1, Ws2, Wn2, W1t, W2t, b1p);

    // layer 1
    agg_mean_bf16<<<NN / 4, 256, 0, stream>>>(xb, csr_ptr, deg_inv, csr_src, aggb);
    gemm1_mfma<<<dim3((NN + 127) / 128, 1), 256, 0, stream>>>(xb, aggb, W1t, b1p, h1b);

    // layer 2
    gemm2_mfma<<<dim3((NN + 127) / 128, 2), 256, 0, stream>>>(h1b, W2t, b2, out, zb);
    agg_add_out<<<NN / 4, 256, 0, stream>>>(zb, csr_ptr, deg_inv, csr_src, out);

    (void)in_sizes; (void)n_in; (void)out_size; (void)ws_size;
}

// Round 4
// 383.574 us; speedup vs baseline: 3.5450x; 1.1926x over previous
//
#include <hip/hip_runtime.h>

#define NN 100000
#define NE 1600000
#define INF 128
#define HID 150
#define NOUT 128

// radix-by-bucket CSR build params
#define NBK 196        // buckets = ceil(NN/512); bucket(d) = d>>9
#define WGS 400        // sort workgroups
#define EPW 4000       // edges per sort workgroup (WGS*EPW == NE exactly)
#define CNTL (NBK * WGS)
#define CAP2 10240     // LDS span cap in buildcsr (mean 8192, +22 sigma)

typedef __attribute__((ext_vector_type(8))) short bf16x8;
typedef __attribute__((ext_vector_type(8))) unsigned short u16x8;
typedef __attribute__((ext_vector_type(4))) float f32x4;

__device__ inline unsigned short f2bf(float f) {
    unsigned int u = __float_as_uint(f);
    u += 0x7fffu + ((u >> 16) & 1u);
    return (unsigned short)(u >> 16);
}
__device__ inline float bflo(unsigned int t) { return __uint_as_float(t << 16); }
__device__ inline float bfhi(unsigned int t) { return __uint_as_float(t & 0xffff0000u); }

// ---------------- radix sort by dst bucket ----------------

__global__ __launch_bounds__(256) void sort1(const int* __restrict__ src,
                                             const int* __restrict__ dst,
                                             unsigned int* __restrict__ chunkw,
                                             int* __restrict__ cntm) {
    __shared__ int hist[NBK];
    __shared__ int off[NBK];
    __shared__ int s[256];
    __shared__ unsigned int buf[EPW];
    int w = blockIdx.x, tid = threadIdx.x;
    int e0 = w * EPW;
    for (int i = tid; i < NBK; i += 256) hist[i] = 0;
    __syncthreads();
    for (int i = tid; i < EPW; i += 256) atomicAdd(&hist[dst[e0 + i] >> 9], 1);
    __syncthreads();
    int v = (tid < NBK) ? hist[tid] : 0;
    s[tid] = v;
    __syncthreads();
    for (int o = 1; o < 256; o <<= 1) {
        int t = (tid >= o) ? s[tid - o] : 0;
        __syncthreads();
        s[tid] += t;
        __syncthreads();
    }
    if (tid < NBK) {
        off[tid] = s[tid] - v;          // exclusive
        cntm[tid * WGS + w] = v;
    }
    __syncthreads();
    for (int i = tid; i < EPW; i += 256) {
        int d = dst[e0 + i];
        int b = d >> 9;
        int p = atomicAdd(&off[b], 1);
        buf[p] = (unsigned int)src[e0 + i] | ((unsigned int)(d & 511) << 17);
    }
    __syncthreads();
    for (int i = tid; i < EPW; i += 256) chunkw[e0 + i] = buf[i];
}

__global__ void scanA(const int* __restrict__ in, int* __restrict__ excl,
                      int* __restrict__ blk_sums, int L) {
    __shared__ int s[256];
    int i = blockIdx.x * 256 + threadIdx.x;
    int d = (i < L) ? in[i] : 0;
    s[threadIdx.x] = d;
    __syncthreads();
    for (int o = 1; o < 256; o <<= 1) {
        int t = (threadIdx.x >= o) ? s[threadIdx.x - o] : 0;
        __syncthreads();
        s[threadIdx.x] += t;
        __syncthreads();
    }
    int incl = s[threadIdx.x];
    if (i < L) excl[i] = incl - d;
    if (threadIdx.x == 255) blk_sums[blockIdx.x] = incl;
}

__global__ void scanB(int* __restrict__ blk_sums, int nb) {
    __shared__ int s[512];
    int t = threadIdx.x;
    int v = (t < nb) ? blk_sums[t] : 0;
    s[t] = v;
    __syncthreads();
    for (int o = 1; o < 512; o <<= 1) {
        int u = (t >= o) ? s[t - o] : 0;
        __syncthreads();
        s[t] += u;
        __syncthreads();
    }
    if (t < nb) blk_sums[t] = s[t] - v;  // exclusive
}

__global__ void scanC(int* __restrict__ excl, const int* __restrict__ blk_sums, int L) {
    int i = blockIdx.x * 256 + threadIdx.x;
    if (i < L) excl[i] += blk_sums[blockIdx.x];
}

__global__ __launch_bounds__(256) void sort3(const unsigned int* __restrict__ chunkw,
                                             const int* __restrict__ cntm,
                                             const int* __restrict__ offm,
                                             unsigned int* __restrict__ bmaj) {
    __shared__ int excl[NBK + 1];
    __shared__ int dbase[NBK];
    __shared__ int s[256];
    int w = blockIdx.x, tid = threadIdx.x;
    int v = (tid < NBK) ? cntm[tid * WGS + w] : 0;
    if (tid < NBK) dbase[tid] = offm[tid * WGS + w];
    s[tid] = v;
    __syncthreads();
    for (int o = 1; o < 256; o <<= 1) {
        int t = (tid >= o) ? s[tid - o] : 0;
        __syncthreads();
        s[tid] += t;
        __syncthreads();
    }
    if (tid < NBK) excl[tid] = s[tid] - v;
    if (tid == 0) excl[NBK] = EPW;
    __syncthreads();
    int e0 = w * EPW;
    for (int i = tid; i < EPW; i += 256) {
        int lo = 0, hi = NBK;
        while (hi - lo > 1) {
            int mid = (lo + hi) >> 1;
            if (excl[mid] <= i) lo = mid; else hi = mid;
        }
        bmaj[dbase[lo] + (i - excl[lo])] = chunkw[e0 + i];
    }
}

__global__ __launch_bounds__(256) void buildcsr(const unsigned int* __restrict__ bmaj,
                                                const int* __restrict__ offm,
                                                int* __restrict__ csr_ptr,
                                                float* __restrict__ deg_inv,
                                                int* __restrict__ csr_src) {
    __shared__ int cnt[512];
    __shared__ int excl[512];
    __shared__ int off[512];
    __shared__ int s[256];
    __shared__ int span[CAP2];
    int b = blockIdx.x, tid = threadIdx.x;
    int base = offm[b * WGS];
    int nxt = (b == NBK - 1) ? NE : offm[(b + 1) * WGS];
    int n = nxt - base;
    if (n > CAP2) n = CAP2;  // memory-safety clamp (never hit for this input)
    for (int i = tid; i < 512; i += 256) cnt[i] = 0;
    __syncthreads();
    for (int i = tid; i < n; i += 256) atomicAdd(&cnt[bmaj[base + i] >> 17], 1);
    __syncthreads();
    int a0 = cnt[2 * tid], a1 = cnt[2 * tid + 1];
    int ps = a0 + a1;
    s[tid] = ps;
    __syncthreads();
    for (int o = 1; o < 256; o <<= 1) {
        int t = (tid >= o) ? s[tid - o] : 0;
        __syncthreads();
        s[tid] += t;
        __syncthreads();
    }
    int ex = s[tid] - ps;
    excl[2 * tid] = ex;
    excl[2 * tid + 1] = ex + a0;
    off[2 * tid] = ex;
    off[2 * tid + 1] = ex + a0;
    __syncthreads();
    for (int l = tid; l < 512; l += 256) {
        int g = b * 512 + l;
        if (g < NN) {
            csr_ptr[g] = base + excl[l];
            int d = cnt[l];
            deg_inv[g] = d > 0 ? 1.0f / (float)d : 0.0f;
        }
    }
    if (b == NBK - 1 && tid == 0) csr_ptr[NN] = NE;
    for (int i = tid; i < n; i += 256) {
        unsigned int wd = bmaj[base + i];
        int l = wd >> 17;
        int p = atomicAdd(&off[l], 1);
        span[p] = (int)(wd & 0x1FFFFu);
    }
    __syncthreads();
    for (int i = tid; i < n; i += 256) csr_src[base + i] = span[i];
}

// ---------------- casts / packing ----------------

__global__ void cast_bf16(const float* __restrict__ in, unsigned short* __restrict__ outb,
                          int n8) {
    int i = blockIdx.x * 256 + threadIdx.x;
    if (i >= n8) return;
    const float4* p = (const float4*)in;
    float4 v0 = p[(size_t)i * 2];
    float4 v1 = p[(size_t)i * 2 + 1];
    u16x8 o = {f2bf(v0.x), f2bf(v0.y), f2bf(v0.z), f2bf(v0.w),
               f2bf(v1.x), f2bf(v1.y), f2bf(v1.z), f2bf(v1.w)};
    ((u16x8*)outb)[i] = o;
}

__global__ void pack_weights(const float* __restrict__ Ws1, const float* __restrict__ Wn1,
                             const float* __restrict__ b1,
                             const float* __restrict__ Ws2, const float* __restrict__ Wn2,
                             unsigned short* __restrict__ W1t, unsigned short* __restrict__ W2t,
                             float* __restrict__ b1p) {
    int id = blockIdx.x * 256 + threadIdx.x;
    if (id < 160 * 256) {
        int n = id >> 8, k = id & 255;
        float v = 0.f;
        if (n < HID) v = (k < 128) ? Ws1[k * HID + n] : Wn1[(k - 128) * HID + n];
        W1t[id] = f2bf(v);
    } else if (id < 160 * 256 + 256 * 160) {
        int id2 = id - 160 * 256;
        int n = id2 / 160, k = id2 - n * 160;
        float v = 0.f;
        if (k < HID) v = (n < 128) ? Ws2[k * 128 + n] : Wn2[k * 128 + (n - 128)];
        W2t[id2] = f2bf(v);
    } else if (id < 160 * 256 + 256 * 160 + 160) {
        int n = id - (160 * 256 + 256 * 160);
        b1p[n] = (n < HID) ? b1[n] : 0.f;
    }
}

// ---------------- aggregation: quad-edge dwordx4 gather ----------------
// Wave layout: rg = lane>>4 (edge subgroup 0..3), ch = lane&15 (16B feature chunk).
// One uint4 gather covers 4 edges' full 256B bf16 rows. acc[8] fp32 per lane
// (features ch*8..ch*8+7 over edges e≡rg mod 4). Final shfl_xor(32,16) merges
// row-groups; lanes 0..15 hold the complete 128-feature row.

#define AGG_ACC(t)                    \
    acc0 += bflo(t.x); acc1 += bfhi(t.x); \
    acc2 += bflo(t.y); acc3 += bfhi(t.y); \
    acc4 += bflo(t.z); acc5 += bfhi(t.z); \
    acc6 += bflo(t.w); acc7 += bfhi(t.w);

__global__ __launch_bounds__(256) void agg_mean_q(
    const unsigned short* __restrict__ featb, const int* __restrict__ csr_ptr,
    const float* __restrict__ deg_inv, const int* __restrict__ csr_src,
    unsigned short* __restrict__ outb) {
    int wid = threadIdx.x >> 6;
    int lane = threadIdx.x & 63;
    int v = blockIdx.x * 4 + wid;
    int start = csr_ptr[v], end = csr_ptr[v + 1];
    int rg = lane >> 4, ch = lane & 15;
    const uint4* f4 = (const uint4*)featb;  // 16 uint4 per 256B row
    float acc0 = 0.f, acc1 = 0.f, acc2 = 0.f, acc3 = 0.f;
    float acc4 = 0.f, acc5 = 0.f, acc6 = 0.f, acc7 = 0.f;
    int e = start;
    for (; e + 8 <= end; e += 8) {
        int s0 = csr_src[e + rg];
        int s1 = csr_src[e + 4 + rg];
        uint4 t0 = f4[(size_t)s0 * 16 + ch];
        uint4 t1 = f4[(size_t)s1 * 16 + ch];
        AGG_ACC(t0);
        AGG_ACC(t1);
    }
    if (e + 4 <= end) {
        int s0 = csr_src[e + rg];
        uint4 t0 = f4[(size_t)s0 * 16 + ch];
        AGG_ACC(t0);
        e += 4;
    }
    int rem = end - e;
    if (rem > 0) {
        int s0 = csr_src[(rg < rem) ? (e + rg) : e];
        uint4 t = f4[(size_t)s0 * 16 + ch];
        float wt = (rg < rem) ? 1.f : 0.f;
        acc0 += wt * bflo(t.x); acc1 += wt * bfhi(t.x);
        acc2 += wt * bflo(t.y); acc3 += wt * bfhi(t.y);
        acc4 += wt * bflo(t.z); acc5 += wt * bfhi(t.z);
        acc6 += wt * bflo(t.w); acc7 += wt * bfhi(t.w);
    }
    acc0 += __shfl_xor(acc0, 32); acc1 += __shfl_xor(acc1, 32);
    acc2 += __shfl_xor(acc2, 32); acc3 += __shfl_xor(acc3, 32);
    acc4 += __shfl_xor(acc4, 32); acc5 += __shfl_xor(acc5, 32);
    acc6 += __shfl_xor(acc6, 32); acc7 += __shfl_xor(acc7, 32);
    acc0 += __shfl_xor(acc0, 16); acc1 += __shfl_xor(acc1, 16);
    acc2 += __shfl_xor(acc2, 16); acc3 += __shfl_xor(acc3, 16);
    acc4 += __shfl_xor(acc4, 16); acc5 += __shfl_xor(acc5, 16);
    acc6 += __shfl_xor(acc6, 16); acc7 += __shfl_xor(acc7, 16);
    if (lane < 16) {
        float di = deg_inv[v];
        u16x8 o = {f2bf(acc0 * di), f2bf(acc1 * di), f2bf(acc2 * di), f2bf(acc3 * di),
                   f2bf(acc4 * di), f2bf(acc5 * di), f2bf(acc6 * di), f2bf(acc7 * di)};
        ((u16x8*)outb)[(size_t)v * 16 + ch] = o;
    }
}

__global__ __launch_bounds__(256) void agg_add_q(
    const unsigned short* __restrict__ zb, const int* __restrict__ csr_ptr,
    const float* __restrict__ deg_inv, const int* __restrict__ csr_src,
    float* __restrict__ out) {
    int wid = threadIdx.x >> 6;
    int lane = threadIdx.x & 63;
    int v = blockIdx.x * 4 + wid;
    int start = csr_ptr[v], end = csr_ptr[v + 1];
    int rg = lane >> 4, ch = lane & 15;
    const uint4* f4 = (const uint4*)zb;
    float acc0 = 0.f, acc1 = 0.f, acc2 = 0.f, acc3 = 0.f;
    float acc4 = 0.f, acc5 = 0.f, acc6 = 0.f, acc7 = 0.f;
    int e = start;
    for (; e + 8 <= end; e += 8) {
        int s0 = csr_src[e + rg];
        int s1 = csr_src[e + 4 + rg];
        uint4 t0 = f4[(size_t)s0 * 16 + ch];
        uint4 t1 = f4[(size_t)s1 * 16 + ch];
        AGG_ACC(t0);
        AGG_ACC(t1);
    }
    if (e + 4 <= end) {
        int s0 = csr_src[e + rg];
        uint4 t0 = f4[(size_t)s0 * 16 + ch];
        AGG_ACC(t0);
        e += 4;
    }
    int rem = end - e;
    if (rem > 0) {
        int s0 = csr_src[(rg < rem) ? (e + rg) : e];
        uint4 t = f4[(size_t)s0 * 16 + ch];
        float wt = (rg < rem) ? 1.f : 0.f;
        acc0 += wt * bflo(t.x); acc1 += wt * bfhi(t.x);
        acc2 += wt * bflo(t.y); acc3 += wt * bfhi(t.y);
        acc4 += wt * bflo(t.z); acc5 += wt * bfhi(t.z);
        acc6 += wt * bflo(t.w); acc7 += wt * bfhi(t.w);
    }
    acc0 += __shfl_xor(acc0, 32); acc1 += __shfl_xor(acc1, 32);
    acc2 += __shfl_xor(acc2, 32); acc3 += __shfl_xor(acc3, 32);
    acc4 += __shfl_xor(acc4, 32); acc5 += __shfl_xor(acc5, 32);
    acc6 += __shfl_xor(acc6, 32); acc7 += __shfl_xor(acc7, 32);
    acc0 += __shfl_xor(acc0, 16); acc1 += __shfl_xor(acc1, 16);
    acc2 += __shfl_xor(acc2, 16); acc3 += __shfl_xor(acc3, 16);
    acc4 += __shfl_xor(acc4, 16); acc5 += __shfl_xor(acc5, 16);
    acc6 += __shfl_xor(acc6, 16); acc7 += __shfl_xor(acc7, 16);
    if (lane < 16) {
        float di = deg_inv[v];
        float4* o4 = (float4*)out;  // 32 float4 per 512B row
        size_t base = (size_t)v * 32 + ch * 2;
        float4 c0 = o4[base];
        float4 c1 = o4[base + 1];
        c0.x += acc0 * di; c0.y += acc1 * di; c0.z += acc2 * di; c0.w += acc3 * di;
        c1.x += acc4 * di; c1.y += acc5 * di; c1.z += acc6 * di; c1.w += acc7 * di;
        o4[base] = c0;
        o4[base + 1] = c1;
    }
}

// ---------------- MFMA GEMMs ----------------

__global__ __launch_bounds__(256) void gemm1_mfma(
    const unsigned short* __restrict__ xb, const unsigned short* __restrict__ aggb,
    const unsigned short* __restrict__ W1t, const float* __restrict__ b1p,
    unsigned short* __restrict__ h1b) {
    __shared__ __align__(16) unsigned short A_lds[128][40];
    __shared__ __align__(16) unsigned short B_lds[160][40];
    int tid = threadIdx.x;
    int m0 = blockIdx.x * 128;
    int w = tid >> 6, lane = tid & 63;
    int lrow = lane & 15, quad = lane >> 4;
    int wr = (w & 1) * 64;
    int wc = (w >> 1) * 80;
    f32x4 acc[4][5];
    #pragma unroll
    for (int r = 0; r < 4; r++)
        #pragma unroll
        for (int c = 0; c < 5; c++) acc[r][c] = (f32x4){0.f, 0.f, 0.f, 0.f};

    for (int k0 = 0; k0 < 256; k0 += 32) {
        __syncthreads();
        #pragma unroll
        for (int i = 0; i < 2; i++) {
            int idx = tid + i * 256;
            int row = idx >> 2, ch = idx & 3;
            int gm = m0 + row, gk = k0 + ch * 8;
            u16x8 val = {0, 0, 0, 0, 0, 0, 0, 0};
            if (gm < NN) {
                const unsigned short* sp = (gk < 128)
                    ? (xb + (size_t)gm * 128 + gk)
                    : (aggb + (size_t)gm * 128 + (gk - 128));
                val = *(const u16x8*)sp;
            }
            *(u16x8*)&A_lds[row][ch * 8] = val;
        }
        #pragma unroll
        for (int i = 0; i < 3; i++) {
            int idx = tid + i * 256;
            if (idx < 640) {
                int n = idx >> 2, ch = idx & 3;
                u16x8 val = *(const u16x8*)(W1t + (size_t)n * 256 + k0 + ch * 8);
                *(u16x8*)&B_lds[n][ch * 8] = val;
            }
        }
        __syncthreads();
        bf16x8 a[4], b[5];
        #pragma unroll
        for (int r = 0; r < 4; r++)
            a[r] = *(const bf16x8*)&A_lds[wr + r * 16 + lrow][quad * 8];
        #pragma unroll
        for (int c = 0; c < 5; c++)
            b[c] = *(const bf16x8*)&B_lds[wc + c * 16 + lrow][quad * 8];
        #pragma unroll
        for (int r = 0; r < 4; r++)
            #pragma unroll
            for (int c = 0; c < 5; c++)
                acc[r][c] = __builtin_amdgcn_mfma_f32_16x16x32_bf16(a[r], b[c], acc[r][c], 0, 0, 0);
    }
    #pragma unroll
    for (int r = 0; r < 4; r++) {
        #pragma unroll
        for (int rr = 0; rr < 4; rr++) {
            int gm = m0 + wr + r * 16 + quad * 4 + rr;
            if (gm < NN) {
                #pragma unroll
                for (int c = 0; c < 5; c++) {
                    int gn = wc + c * 16 + lrow;
                    float val = acc[r][c][rr] + b1p[gn];
                    val = val > 0.f ? val : 0.f;
                    h1b[(size_t)gm * 160 + gn] = f2bf(val);
                }
            }
        }
    }
}

__global__ __launch_bounds__(256) void gemm2_mfma(
    const unsigned short* __restrict__ h1b, const unsigned short* __restrict__ W2t,
    const float* __restrict__ b2, float* __restrict__ out,
    unsigned short* __restrict__ zb) {
    __shared__ __align__(16) unsigned short A_lds[128][40];
    __shared__ __align__(16) unsigned short B_lds[128][40];
    int tid = threadIdx.x;
    int m0 = blockIdx.x * 128;
    int n0 = blockIdx.y * 128;
    int w = tid >> 6, lane = tid & 63;
    int lrow = lane & 15, quad = lane >> 4;
    int wr = (w & 1) * 64;
    int wc = (w >> 1) * 64;
    f32x4 acc[4][4];
    #pragma unroll
    for (int r = 0; r < 4; r++)
        #pragma unroll
        for (int c = 0; c < 4; c++) acc[r][c] = (f32x4){0.f, 0.f, 0.f, 0.f};

    for (int k0 = 0; k0 < 160; k0 += 32) {
        __syncthreads();
        #pragma unroll
        for (int i = 0; i < 2; i++) {
            int idx = tid + i * 256;
            int row = idx >> 2, ch = idx & 3;
            int gm = m0 + row;
            u16x8 val = {0, 0, 0, 0, 0, 0, 0, 0};
            if (gm < NN) val = *(const u16x8*)(h1b + (size_t)gm * 160 + k0 + ch * 8);
            *(u16x8*)&A_lds[row][ch * 8] = val;
        }
        #pragma unroll
        for (int i = 0; i < 2; i++) {
            int idx = tid + i * 256;
            int n = idx >> 2, ch = idx & 3;
            u16x8 val = *(const u16x8*)(W2t + (size_t)(n0 + n) * 160 + k0 + ch * 8);
            *(u16x8*)&B_lds[n][ch * 8] = val;
        }
        __syncthreads();
        bf16x8 a[4], b[4];
        #pragma unroll
        for (int r = 0; r < 4; r++)
            a[r] = *(const bf16x8*)&A_lds[wr + r * 16 + lrow][quad * 8];
        #pragma unroll
        for (int c = 0; c < 4; c++)
            b[c] = *(const bf16x8*)&B_lds[wc + c * 16 + lrow][quad * 8];
        #pragma unroll
        for (int r = 0; r < 4; r++)
            #pragma unroll
            for (int c = 0; c < 4; c++)
                acc[r][c] = __builtin_amdgcn_mfma_f32_16x16x32_bf16(a[r], b[c], acc[r][c], 0, 0, 0);
    }
    #pragma unroll
    for (int r = 0; r < 4; r++) {
        #pragma unroll
        for (int rr = 0; rr < 4; rr++) {
            int gm = m0 + wr + r * 16 + quad * 4 + rr;
            if (gm < NN) {
                #pragma unroll
                for (int c = 0; c < 4; c++) {
                    int gn = wc + c * 16 + lrow;
                    float val = acc[r][c][rr];
                    if (n0 == 0) {
                        out[(size_t)gm * 128 + gn] = val + b2[gn];
                    } else {
                        zb[(size_t)gm * 128 + gn] = f2bf(val);
                    }
                }
            }
        }
    }
}

// ---------------- launch ----------------

extern "C" void kernel_launch(void* const* d_in, const int* in_sizes, int n_in,
                              void* d_out, int out_size, void* d_ws, size_t ws_size,
                              hipStream_t stream) {
    const float* x   = (const float*)d_in[0];
    const int* src   = (const int*)d_in[1];
    const int* dst   = (const int*)d_in[2];
    const float* Ws1 = (const float*)d_in[3];
    const float* Wn1 = (const float*)d_in[4];
    const float* b1  = (const float*)d_in[5];
    const float* Ws2 = (const float*)d_in[6];
    const float* Wn2 = (const float*)d_in[7];
    const float* b2  = (const float*)d_in[8];
    float* out = (float*)d_out;

    char* p = (char*)d_ws;
    auto carve = [&](size_t bytes) {
        void* r = (void*)p;
        p += (bytes + 255) & ~(size_t)255;
        return r;
    };
    int*   csr_ptr  = (int*)carve((size_t)(NN + 1) * 4);
    float* deg_inv  = (float*)carve((size_t)NN * 4);
    int*   csr_src  = (int*)carve((size_t)NE * 4);
    int*   cntm     = (int*)carve((size_t)CNTL * 4);
    int*   offm     = (int*)carve((size_t)CNTL * 4);
    int*   blk2     = (int*)carve(512 * 4);
    unsigned short* xb   = (unsigned short*)carve((size_t)NN * 128 * 2);
    unsigned short* aggb = (unsigned short*)carve((size_t)NN * 128 * 2);
    unsigned short* zb   = (unsigned short*)carve((size_t)NN * 128 * 2);
    unsigned short* W1t  = (unsigned short*)carve(160 * 256 * 2);
    unsigned short* W2t  = (unsigned short*)carve(256 * 160 * 2);
    float* b1p           = (float*)carve(160 * 4);
    unsigned short* h1b  = (unsigned short*)carve((size_t)NN * 160 * 2);
    // sort buffers alias h1b's 32 MB region (dead until gemm1 runs)
    unsigned int* chunkw = (unsigned int*)h1b;                            // 6.4 MB
    unsigned int* bmaj   = (unsigned int*)((char*)h1b + (size_t)NE * 4);  // 6.4 MB

    // CSR build: radix sort by bucket, no global atomics
    sort1<<<WGS, 256, 0, stream>>>(src, dst, chunkw, cntm);
    const int SB = (CNTL + 255) / 256;  // 307
    scanA<<<SB, 256, 0, stream>>>(cntm, offm, blk2, CNTL);
    scanB<<<1, 512, 0, stream>>>(blk2, SB);
    scanC<<<SB, 256, 0, stream>>>(offm, blk2, CNTL);
    sort3<<<WGS, 256, 0, stream>>>(chunkw, cntm, offm, bmaj);
    buildcsr<<<NBK, 256, 0, stream>>>(bmaj, offm, csr_ptr, deg_inv, csr_src);

    // casts + weight packing
    cast_bf16<<<(NN * 128 / 8 + 255) / 256, 256, 0, stream>>>(x, xb, NN * 128 / 8);
    pack_weights<<<(160 * 256 + 256 * 160 + 160 + 255) / 256, 256, 0, stream>>>(
        Ws1, Wn1, b1, Ws2, Wn2, W1t, W2t, b1p);

    // layer 1
    agg_mean_q<<<NN / 4, 256, 0, stream>>>(xb, csr_ptr, deg_inv, csr_src, aggb);
    gemm1_mfma<<<dim3((NN + 127) / 128, 1), 256, 0, stream>>>(xb, aggb, W1t, b1p, h1b);

    // layer 2
    gemm2_mfma<<<dim3((NN + 127) / 128, 2), 256, 0, stream>>>(h1b, W2t, b2, out, zb);
    agg_add_q<<<NN / 4, 256, 0, stream>>>(zb, csr_ptr, deg_inv, csr_src, out);

    (void)in_sizes; (void)n_in; (void)out_size; (void)ws_size;
}